// Round 10
// baseline (951.141 us; speedup 1.0000x reference)
//
#include <hip/hip_runtime.h>
#include <hip/hip_bf16.h>
#include <stdint.h>

// MoE FFN: sigmoid router (group-limited greedy top-8 of 64), SwiGLU experts
// (1024->512->1024) + shared expert (1024->2048->1024). All inputs fp32.
// R13: transpose prepass CONSOLIDATED + pipelined. A/B across R7/R10/R12
// proves the 6-launch transpose prepass costs ~230-280us (~2.5 TB/s), and
// it never appears in top-5 (each dispatch just under the GEMM's 122us).
// Now: ONE kernel for gate+up+down (z=192, 4x work per block: 64x256 region
// as four 64x64 LDS subtiles, next subtile's loads issued before the
// store phase) + ONE for the 3 shared-expert weights (z=3). The merged big
// dispatch (~130-200us) will surface in top-5 -> direct measurement.
// GEMM kept R12-exact (122us fused routed, proven). Swizzle thread retired:
// bank math shows [row][64B] b128 reads are already uniform (R10 null).

#define S_TOK 4096
#define C_DIM 1024
#define E_NUM 64
#define H_DIM 512
#define HS_DIM 2048
#define ROWS_TOTAL (S_TOK * 8)
#define T_TILES 320   // ROWS_TOTAL/128 + E_NUM upper bound on routed m-tiles

typedef __attribute__((ext_vector_type(8))) short short8;
typedef __attribute__((ext_vector_type(4))) float f32x4;
typedef __attribute__((ext_vector_type(2))) unsigned int uint2v;

static __device__ __forceinline__ unsigned short f2bf(float f) {
    union { float f; uint32_t u; } v; v.f = f;
    uint32_t u = v.u;
    u += 0x7fffu + ((u >> 16) & 1u);   // RNE
    return (unsigned short)(u >> 16);
}

static __device__ __forceinline__ uint32_t cvtpk(float a, float b) {
    uint32_t r;
    asm("v_cvt_pk_bf16_f32 %0, %1, %2" : "=v"(r) : "v"(a), "v"(b));
    return r;
}

static __device__ __forceinline__ void gl2lds16(const void* g, void* l) {
    __builtin_amdgcn_global_load_lds(
        (const __attribute__((address_space(1))) uint32_t*)g,
        (__attribute__((address_space(3))) uint32_t*)l, 16, 0, 0);
}

// ---------------- router part 1: scores = sigmoid(x @ rw^T), fp32 ----------------
__global__ __launch_bounds__(256)
void router_scores_k(const float* __restrict__ x, const float* __restrict__ rw,
                     float* __restrict__ scores, int* __restrict__ counts) {
    if (blockIdx.x == 0 && threadIdx.x < E_NUM) counts[threadIdx.x] = 0;
    int t0 = blockIdx.x * 32;
    __shared__ float xs[32][36];
    __shared__ float wsm[64][36];
    int t = threadIdx.x;
    int tx = t & 15, ty = t >> 4;
    float acc[2][4] = {};
    for (int k0 = 0; k0 < C_DIM; k0 += 32) {
        {
            int r = t >> 3, c = t & 7;
            *(float4*)&xs[r][c * 4] = *(const float4*)(x + (size_t)(t0 + r) * C_DIM + k0 + c * 4);
        }
        #pragma unroll
        for (int i = 0; i < 2; i++) {
            int idx = t + 256 * i;
            int r = idx >> 3, c = idx & 7;
            *(float4*)&wsm[r][c * 4] = *(const float4*)(rw + (size_t)r * C_DIM + k0 + c * 4);
        }
        __syncthreads();
        #pragma unroll
        for (int kk = 0; kk < 32; kk += 4) {
            float4 a0 = *(const float4*)&xs[ty * 2 + 0][kk];
            float4 a1 = *(const float4*)&xs[ty * 2 + 1][kk];
            #pragma unroll
            for (int j = 0; j < 4; j++) {
                float4 b = *(const float4*)&wsm[tx * 4 + j][kk];
                acc[0][j] += a0.x * b.x + a0.y * b.y + a0.z * b.z + a0.w * b.w;
                acc[1][j] += a1.x * b.x + a1.y * b.y + a1.z * b.z + a1.w * b.w;
            }
        }
        __syncthreads();
    }
    #pragma unroll
    for (int i = 0; i < 2; i++)
        #pragma unroll
        for (int j = 0; j < 4; j++)
            scores[(size_t)(t0 + ty * 2 + i) * E_NUM + tx * 4 + j] =
                1.f / (1.f + __expf(-acc[i][j]));
}

// ---------------- router part 2: wave-parallel grouped top-k ----------------
__global__ __launch_bounds__(256)
void topk_k(const float* __restrict__ scores, const float* __restrict__ ebias,
            int* __restrict__ topk_idx, float* __restrict__ topk_w,
            int* __restrict__ counts) {
    int t = blockIdx.x * 4 + (threadIdx.x >> 6);
    int e = threadIdx.x & 63;
    float sc = scores[(size_t)t * E_NUM + e];
    float sb = sc + ebias[e];
    float m1 = sb, m2 = -1e30f;
    #pragma unroll
    for (int off = 1; off <= 4; off <<= 1) {
        float o1 = __shfl_xor(m1, off);
        float o2 = __shfl_xor(m2, off);
        float hi = fmaxf(m1, o1), lo = fminf(m1, o1);
        m2 = fmaxf(lo, fmaxf(m2, o2));
        m1 = hi;
    }
    float grp = m1 + m2;
    float grpv[8];
    #pragma unroll
    for (int g = 0; g < 8; g++) grpv[g] = __shfl(grp, g * 8);
    unsigned gsel = 0;
    #pragma unroll
    for (int k = 0; k < 4; k++) {
        float best = -1e30f; int bi = 0;
        #pragma unroll
        for (int g = 0; g < 8; g++)
            if (!((gsel >> g) & 1) && grpv[g] > best) { best = grpv[g]; bi = g; }
        gsel |= 1u << bi;
    }
    float val = ((gsel >> (e >> 3)) & 1) ? sb : -1e30f;
    int idx[8]; float sv[8]; float wsum = 0.f;
    #pragma unroll
    for (int k = 0; k < 8; k++) {
        uint32_t u = __float_as_uint(val);
        uint32_t mu = (u & 0x80000000u) ? ~u : (u | 0x80000000u);
        unsigned long long key = ((unsigned long long)mu << 6) | (unsigned long long)(63 - e);
        #pragma unroll
        for (int off = 32; off; off >>= 1) {
            unsigned long long ok = __shfl_xor(key, off);
            if (ok > key) key = ok;
        }
        int win = 63 - (int)(key & 63ull);
        idx[k] = win;
        sv[k] = __shfl(sc, win);
        wsum += sv[k];
        if (e == win) val = -1e30f;
    }
    float inv = 1.f / (wsum + 1e-20f);
    if (e < 8) {
        topk_idx[t * 8 + e] = idx[e];
        topk_w[t * 8 + e] = sv[e] * inv;
        atomicAdd(&counts[idx[e]], 1);
    }
}

// exclusive scan over 64 expert counts + m-tile worklist build, one wave
__global__ void scan_k(const int* __restrict__ counts, int* __restrict__ base,
                       int* __restrict__ cursor, int* __restrict__ tile_e,
                       int* __restrict__ tile_m0) {
    int e = threadIdx.x;
    int c = counts[e];
    int s = c;
    #pragma unroll
    for (int off = 1; off < 64; off <<= 1) {
        int o = __shfl_up(s, off);
        if (e >= off) s += o;
    }
    int ex = s - c;
    base[e] = ex;
    cursor[e] = ex;
    int nt = (c + 127) >> 7;
    int ts = nt;
    #pragma unroll
    for (int off = 1; off < 64; off <<= 1) {
        int o = __shfl_up(ts, off);
        if (e >= off) ts += o;
    }
    int tb = ts - nt;
    for (int i = 0; i < nt; i++) { tile_e[tb + i] = e; tile_m0[tb + i] = i * 128; }
    int total = __shfl(ts, 63);
    for (int j = total + e; j < T_TILES; j += 64) tile_e[j] = -1;
}

__global__ void scatter_k(const int* __restrict__ topk_idx, const float* __restrict__ topk_w,
                          int* __restrict__ cursor, int* __restrict__ row_token,
                          float* __restrict__ row_wgt, int* __restrict__ pos_of) {
    int i = blockIdx.x * blockDim.x + threadIdx.x;
    int e = topk_idx[i];
    int pos = atomicAdd(&cursor[e], 1);
    row_token[pos] = i >> 3;
    row_wgt[pos] = topk_w[i];
    pos_of[i] = pos;
}

// ---------------- combine: out[t] += sum_k O[pos_of[t*8+k]] (weights pre-applied) ---
__global__ __launch_bounds__(256)
void combine_k(const float* __restrict__ O, const int* __restrict__ pos_of,
               float* __restrict__ out) {
    int t = blockIdx.x;
    int c = threadIdx.x;
    float4 s = ((const float4*)(out + (size_t)t * C_DIM))[c];
    int p[8];
    #pragma unroll
    for (int k = 0; k < 8; k++) p[k] = pos_of[t * 8 + k];
    #pragma unroll
    for (int k = 0; k < 8; k++) {
        float4 v = ((const float4*)(O + (size_t)p[k] * C_DIM))[c];
        s.x += v.x; s.y += v.y; s.z += v.z; s.w += v.w;
    }
    ((float4*)(out + (size_t)t * C_DIM))[c] = s;
}

// ---------------- prepass: fp32 -> bf16 elementwise (x) ----------------
__global__ void cvt_bf16_k(const float* __restrict__ in, unsigned short* __restrict__ out, int n8) {
    int i = blockIdx.x * blockDim.x + threadIdx.x;
    if (i >= n8) return;
    float4 v0 = ((const float4*)in)[2 * i];
    float4 v1 = ((const float4*)in)[2 * i + 1];
    unsigned short t[8] = { f2bf(v0.x), f2bf(v0.y), f2bf(v0.z), f2bf(v0.w),
                            f2bf(v1.x), f2bf(v1.y), f2bf(v1.z), f2bf(v1.w) };
    ((uint4*)out)[i] = *(uint4*)t;
}

// ---------------- prepass: batched fp32 [R][C] -> bf16 [C][R] transpose ----------
// Block: 64 rows x 256 cols = four 64x64 subtiles through one LDS buffer.
// Subtile: 4 float4 loads/thread (next subtile issued before store phase),
// 8 cvt_pk, 4 ds_write_b64 (LP=68 pad), sync, 4 ds_read_b64 + 2x16B stores.
// BIG=1: z=192 -> gate(0-63)/up(64-127)/down(128-191).
// BIG=0: z=3   -> sh_gate/sh_up/sh_down.
#define LP 68
template<bool BIG>
__global__ __launch_bounds__(256)
void transpose_wide_k(const float* __restrict__ p0, const float* __restrict__ p1,
                      const float* __restrict__ p2,
                      unsigned short* __restrict__ q0, unsigned short* __restrict__ q1,
                      unsigned short* __restrict__ q2) {
    int z = blockIdx.z;
    const float* in; unsigned short* out; int R, C;
    if (BIG) {
        int slice;
        if (z < 64)       { slice = z;       in = p0; out = q0; R = C_DIM; C = H_DIM; }
        else if (z < 128) { slice = z - 64;  in = p1; out = q1; R = C_DIM; C = H_DIM; }
        else              { slice = z - 128; in = p2; out = q2; R = H_DIM; C = C_DIM; }
        in  += (size_t)slice * R * C;
        out += (size_t)slice * R * C;
    } else {
        if (z == 0)      { in = p0; out = q0; R = C_DIM;  C = HS_DIM; }
        else if (z == 1) { in = p1; out = q1; R = C_DIM;  C = HS_DIM; }
        else             { in = p2; out = q2; R = HS_DIM; C = C_DIM; }
    }
    int r0 = blockIdx.y * 64, c0 = blockIdx.x * 256;
    if (r0 >= R || c0 >= C) return;

    __shared__ unsigned short T[64 * LP];
    int t = threadIdx.x;
    int cg = t & 15, rg = t >> 4;
    int n = t >> 2, q = t & 3;

    float4 cur[4], nxt[4];
    auto ld = [&](int s, float4 (&m)[4]) {
        const float* ip = in + (size_t)(r0 + rg * 4) * C + c0 + s * 64 + cg * 4;
        m[0] = *(const float4*)(ip);
        m[1] = *(const float4*)(ip + C);
        m[2] = *(const float4*)(ip + 2 * C);
        m[3] = *(const float4*)(ip + 3 * C);
    };
    ld(0, cur);
    #pragma unroll
    for (int s = 0; s < 4; s++) {
        if (s < 3) ld(s + 1, nxt);          // prefetch: flies during cvt+LDS+stores
        uint2v wv;
        unsigned short* tb = &T[(cg * 4) * LP + rg * 4];
        wv[0] = cvtpk(cur[0].x, cur[1].x); wv[1] = cvtpk(cur[2].x, cur[3].x);
        *(uint2v*)(tb)          = wv;
        wv[0] = cvtpk(cur[0].y, cur[1].y); wv[1] = cvtpk(cur[2].y, cur[3].y);
        *(uint2v*)(tb + LP)     = wv;
        wv[0] = cvtpk(cur[0].z, cur[1].z); wv[1] = cvtpk(cur[2].z, cur[3].z);
        *(uint2v*)(tb + 2 * LP) = wv;
        wv[0] = cvtpk(cur[0].w, cur[1].w); wv[1] = cvtpk(cur[2].w, cur[3].w);
        *(uint2v*)(tb + 3 * LP) = wv;
        __syncthreads();
        const unsigned short* rb = &T[n * LP + q * 16];
        uint2v a0 = *(const uint2v*)(rb);
        uint2v a1 = *(const uint2v*)(rb + 4);
        uint2v a2 = *(const uint2v*)(rb + 8);
        uint2v a3 = *(const uint2v*)(rb + 12);
        unsigned short* op = out + (size_t)(c0 + s * 64 + n) * R + r0 + q * 16;
        uint4 s0, s1;
        s0.x = a0[0]; s0.y = a0[1]; s0.z = a1[0]; s0.w = a1[1];
        s1.x = a2[0]; s1.y = a2[1]; s1.z = a3[0]; s1.w = a3[1];
        *(uint4*)op = s0;
        *(uint4*)(op + 8) = s1;
        __syncthreads();
        #pragma unroll
        for (int i = 0; i < 4; i++) cur[i] = nxt[i];
    }
}

// ---------------- GEMM: C[M,N] = A[M,K] @ Bt[N,K]^T, bf16 in, fp32 acc ----------------
// FUSED: tile 128x64 (wave 64x32, acc1+acc2 = 64 regs, LDS 48 KB, 3 blocks/CU)
// non-FUSED: tile 128x128 (wave 64x64, acc 64 regs, LDS 48 KB, 3 blocks/CU)
// 3-slot LDS ring, 2-deep prefetch, counted vmcnt(4) + raw barriers.
// EPI: 0 = SwiGLU(acc1)*acc2 -> bf16; 1 = f32 store; 2 = f32 scaled store
template<bool FUSED, bool GATHER, bool WL, int EPI>
__global__ __launch_bounds__(256, 3)
void gemm2_k(const short* __restrict__ A, const short* __restrict__ B1t,
             const short* __restrict__ B2t, void* __restrict__ Cout,
             int M, int N, int K,
             const int* __restrict__ counts, const int* __restrict__ base,
             const int* __restrict__ row_token, const float* __restrict__ row_wgt,
             const int* __restrict__ tile_e, const int* __restrict__ tile_m0) {
    constexpr int BN = FUSED ? 64 : 128;
    constexpr int NJ = FUSED ? 2 : 4;

    int e = 0, m0, Mrows, rowbase = 0;
    if (WL) {
        e = tile_e[blockIdx.y];
        if (e < 0) return;
        m0 = tile_m0[blockIdx.y];
        Mrows = counts[e];
        rowbase = base[e];
    } else {
        m0 = blockIdx.y * 128;
        Mrows = M;
    }
    int n0 = blockIdx.x * BN;
    const short* B1 = B1t + (WL ? (size_t)e * N * K : 0) + (size_t)n0 * K;
    const short* B2 = FUSED ? (B2t + (WL ? (size_t)e * N * K : 0) + (size_t)n0 * K) : nullptr;

    __shared__ short As[3 * 4096];                       // 3 x 128x32
    __shared__ short Bs1[FUSED ? 3 * 2048 : 3 * 4096];   // 3 x BNx32
    __shared__ short Bs2[FUSED ? 3 * 2048 : 16];

    int tid = threadIdx.x;
    int lane = tid & 63, w = tid >> 6;
    int wr = w >> 1, wc = w & 1;
    int quad = lane >> 4, l16 = lane & 15;
    int sr = lane >> 2, sc = lane & 3;

    const short* aptr[2];
    const short* b1ptr[2];
    const short* b2ptr;
    #pragma unroll
    for (int i = 0; i < 2; i++) {
        int row = w * 32 + i * 16 + sr;
        int mrow = m0 + row;
        int cl = mrow < Mrows ? mrow : (Mrows - 1);
        size_t arow;
        if (GATHER)  arow = (size_t)row_token[rowbase + cl];
        else if (WL) arow = (size_t)(rowbase + cl);
        else         arow = (size_t)mrow;
        aptr[i] = A + arow * K + sc * 8;
    }
    if constexpr (FUSED) {
        int row = w * 16 + sr;                 // 4 waves cover 64 B-rows
        b1ptr[0] = B1 + (size_t)row * K + sc * 8;
        b2ptr    = B2 + (size_t)row * K + sc * 8;
    } else {
        #pragma unroll
        for (int i = 0; i < 2; i++) {
            int row = w * 32 + i * 16 + sr;
            b1ptr[i] = B1 + (size_t)row * K + sc * 8;
        }
        b2ptr = nullptr;
    }

    f32x4 acc1[4][NJ] = {};
    f32x4 acc2[FUSED ? 4 : 1][NJ] = {};

    const int nk = K >> 5;
    auto stage = [&](int slot) {
        #pragma unroll
        for (int i = 0; i < 2; i++) {
            gl2lds16(aptr[i], &As[slot * 4096 + (w * 32 + i * 16) * 32]);
            aptr[i] += 32;
        }
        if constexpr (FUSED) {
            gl2lds16(b1ptr[0], &Bs1[slot * 2048 + w * 512]); b1ptr[0] += 32;
            gl2lds16(b2ptr,    &Bs2[slot * 2048 + w * 512]); b2ptr += 32;
        } else {
            #pragma unroll
            for (int i = 0; i < 2; i++) {
                gl2lds16(b1ptr[i], &Bs1[slot * 4096 + (w * 32 + i * 16) * 32]);
                b1ptr[i] += 32;
            }
        }
    };
    stage(0);
    if (nk > 1) stage(1);

    int slot = 0, nslot = 2;
    for (int t = 0; t < nk; t++) {
        // wait for stage t only: leave the 1 in-flight stage (4 loads/wave) pending
        if (t + 1 < nk) {
            asm volatile("s_waitcnt vmcnt(4)" ::: "memory");
        } else {
            asm volatile("s_waitcnt vmcnt(0)" ::: "memory");
        }
        __builtin_amdgcn_s_barrier();
        __builtin_amdgcn_sched_barrier(0);   // nothing crosses the barrier (rule #18)

        if (t + 2 < nk) stage(nslot);

        short8 a[4], b1[NJ], b2[NJ];
        #pragma unroll
        for (int i = 0; i < 4; i++)
            a[i] = *(const short8*)&As[slot * 4096 + (wr * 64 + i * 16 + l16) * 32 + quad * 8];
        if constexpr (FUSED) {
            #pragma unroll
            for (int j = 0; j < NJ; j++) {
                b1[j] = *(const short8*)&Bs1[slot * 2048 + (wc * 32 + j * 16 + l16) * 32 + quad * 8];
                b2[j] = *(const short8*)&Bs2[slot * 2048 + (wc * 32 + j * 16 + l16) * 32 + quad * 8];
            }
        } else {
            #pragma unroll
            for (int j = 0; j < NJ; j++)
                b1[j] = *(const short8*)&Bs1[slot * 4096 + (wc * 64 + j * 16 + l16) * 32 + quad * 8];
        }
        #pragma unroll
        for (int i = 0; i < 4; i++)
            #pragma unroll
            for (int j = 0; j < NJ; j++) {
                acc1[i][j] = __builtin_amdgcn_mfma_f32_16x16x32_bf16(a[i], b1[j], acc1[i][j], 0, 0, 0);
                if (FUSED)
                    acc2[i][j] = __builtin_amdgcn_mfma_f32_16x16x32_bf16(a[i], b2[j], acc2[i][j], 0, 0, 0);
            }
        slot = (slot == 2) ? 0 : slot + 1;
        nslot = (nslot == 2) ? 0 : nslot + 1;
    }

    constexpr int CB = FUSED ? 32 : 64;
    #pragma unroll
    for (int i = 0; i < 4; i++) {
        #pragma unroll
        for (int rr = 0; rr < 4; rr++) {
            int row = m0 + wr * 64 + i * 16 + quad * 4 + rr;
            if (row >= Mrows) continue;
            size_t orow = WL ? (size_t)(rowbase + row) : (size_t)row;
            float scl = 0.f;
            if (EPI == 2) scl = row_wgt[rowbase + row];
            #pragma unroll
            for (int j = 0; j < NJ; j++) {
                int n = n0 + wc * CB + j * 16 + l16;
                float v = acc1[i][j][rr];
                if (EPI == 0) {
                    float u = acc2[i][j][rr];
                    float h = v / (1.f + __expf(-v)) * u;
                    ((unsigned short*)Cout)[orow * N + n] = f2bf(h);
                } else if (EPI == 1) {
                    ((float*)Cout)[orow * N + n] = v;
                } else {
                    ((float*)Cout)[orow * N + n] = v * scl;
                }
            }
        }
    }
}

// ---------------- launch ----------------
extern "C" void kernel_launch(void* const* d_in, const int* in_sizes, int n_in,
                              void* d_out, int out_size, void* d_ws, size_t ws_size,
                              hipStream_t stream) {
    const float* x        = (const float*)d_in[0];
    const float* router_w = (const float*)d_in[1];
    const float* e_bias   = (const float*)d_in[2];
    const float* gate_w   = (const float*)d_in[3];
    const float* up_w     = (const float*)d_in[4];
    const float* down_w   = (const float*)d_in[5];
    const float* sh_gate  = (const float*)d_in[6];
    const float* sh_up    = (const float*)d_in[7];
    const float* sh_down  = (const float*)d_in[8];
    float* out = (float*)d_out;
    char* ws = (char*)d_ws;

    int*   counts    = (int*)(ws);
    int*   base      = (int*)(ws + 256);
    int*   cursor    = (int*)(ws + 512);
    int*   topk_idx  = (int*)(ws + 1024);
    float* topk_w    = (float*)(ws + 1024 + 131072);
    int*   row_token = (int*)(ws + 1024 + 2 * 131072);
    float* row_wgt   = (float*)(ws + 1024 + 3 * 131072);
    float* scoresbuf = (float*)(ws + 1024 + 4 * 131072);           // 1 MB
    int*   pos_of    = (int*)(ws + 1664 * 1024);                   // 128 KB
    int*   tile_e    = (int*)(ws + 1800 * 1024);                   // 1.25 KB
    int*   tile_m0   = (int*)(ws + 1808 * 1024);                   // 1.25 KB
    const size_t MB = 1u << 20;
    unsigned short* xb        = (unsigned short*)(ws + 2 * MB);    // 8 MB
    unsigned short* Hs        = (unsigned short*)(ws + 10 * MB);   // 16 MB
    unsigned short* Hr        = (unsigned short*)(ws + 26 * MB);   // 32 MB
    unsigned short* sh_gate_t = (unsigned short*)(ws + 58 * MB);   // 4 MB
    unsigned short* sh_up_t   = (unsigned short*)(ws + 62 * MB);   // 4 MB
    unsigned short* sh_down_t = (unsigned short*)(ws + 66 * MB);   // 4 MB
    unsigned short* gate_t    = (unsigned short*)(ws + 70 * MB);   // 64 MB
    unsigned short* up_t      = (unsigned short*)(ws + 134 * MB);  // 64 MB
    unsigned short* down_t    = (unsigned short*)(ws + 198 * MB);  // 64 MB -> 262 MB
    // O overlays gate_t+up_t (dead after routed fused GEMM): 32768x1024 f32 = 128 MiB
    float* O = (float*)(ws + 70 * MB);

    // ---- routing ----
    router_scores_k<<<S_TOK / 32, 256, 0, stream>>>(x, router_w, scoresbuf, counts);
    topk_k<<<S_TOK / 4, 256, 0, stream>>>(scoresbuf, e_bias, topk_idx, topk_w, counts);
    scan_k<<<1, 64, 0, stream>>>(counts, base, cursor, tile_e, tile_m0);
    scatter_k<<<ROWS_TOTAL / 256, 256, 0, stream>>>(topk_idx, topk_w, cursor, row_token, row_wgt, pos_of);

    // ---- prepass: bf16 conversion + consolidated weight transposes ----
    cvt_bf16_k<<<S_TOK * C_DIM / 8 / 256, 256, 0, stream>>>(x, xb, S_TOK * C_DIM / 8);
    // big: gate/up [1024][512] (x<2,y<16), down [512][1024] (x<4,y<8); grid covers max
    transpose_wide_k<true><<<dim3(4, 16, 192), 256, 0, stream>>>(
        gate_w, up_w, down_w, gate_t, up_t, down_t);
    // shared: sh_gate/sh_up [1024][2048] (x<8,y<16), sh_down [2048][1024] (x<4,y<32)
    transpose_wide_k<false><<<dim3(8, 32, 3), 256, 0, stream>>>(
        sh_gate, sh_up, sh_down, sh_gate_t, sh_up_t, sh_down_t);

    // ---- shared expert ----
    gemm2_k<true, false, false, 0><<<dim3(HS_DIM / 64, S_TOK / 128, 1), 256, 0, stream>>>(
        (const short*)xb, (const short*)sh_gate_t, (const short*)sh_up_t, Hs,
        S_TOK, HS_DIM, C_DIM, nullptr, nullptr, nullptr, nullptr, nullptr, nullptr);
    gemm2_k<false, false, false, 1><<<dim3(C_DIM / 128, S_TOK / 128, 1), 256, 0, stream>>>(
        (const short*)Hs, (const short*)sh_down_t, nullptr, out,
        S_TOK, C_DIM, HS_DIM, nullptr, nullptr, nullptr, nullptr, nullptr, nullptr);

    // ---- routed experts (worklist-balanced) ----
    gemm2_k<true, true, true, 0><<<dim3(H_DIM / 64, T_TILES, 1), 256, 0, stream>>>(
        (const short*)xb, (const short*)gate_t, (const short*)up_t, Hr,
        0, H_DIM, C_DIM, counts, base, row_token, row_wgt, tile_e, tile_m0);
    gemm2_k<false, false, true, 2><<<dim3(C_DIM / 128, T_TILES, 1), 256, 0, stream>>>(
        (const short*)Hr, (const short*)down_t, nullptr, O,
        0, C_DIM, H_DIM, counts, base, row_token, row_wgt, tile_e, tile_m0);

    // ---- combine routed into out (out already holds shared-expert result) ----
    combine_k<<<S_TOK, 256, 0, stream>>>(O, pos_of, out);
}

// Round 11
// 943.482 us; speedup vs baseline: 1.0081x; 1.0081x over previous
//
#include <hip/hip_runtime.h>
#include <hip/hip_bf16.h>
#include <stdint.h>

// MoE FFN: sigmoid router (group-limited greedy top-8 of 64), SwiGLU experts
// (1024->512->1024) + shared expert (1024->2048->1024). All inputs fp32.
// R14: TRANSPOSE DELETED (R13 measured it directly: 181us @ 2.2 TB/s,
// scatter-bound, unfixable). Prepass is now a pure elementwise fp32->bf16
// cvt in the native [K][N] layout (both sides sequential, ~5.5 TB/s).
// GEMM B-path: gl2lds from bf16 [K][N] with PER-LANE pre-swizzled global
// sources (m173: LDS dest stays linear & identical to R12; content lands in
// subtiled [k/4][n/16][4][16] order), fragments via ds_read_b64_tr_b16
// (addressing copied from R11, which PASSED correctness; only its staging
// was slow). vmcnt(4) ring schedule identical to R12 (same 4 gl2lds/wave).
// A-path, worklist (R6), combine (R5) unchanged.

#define S_TOK 4096
#define C_DIM 1024
#define E_NUM 64
#define H_DIM 512
#define HS_DIM 2048
#define ROWS_TOTAL (S_TOK * 8)
#define T_TILES 320   // ROWS_TOTAL/128 + E_NUM upper bound on routed m-tiles

typedef __attribute__((ext_vector_type(8))) short short8;
typedef __attribute__((ext_vector_type(4))) float f32x4;
typedef __attribute__((ext_vector_type(2))) unsigned int uint2v;

static __device__ __forceinline__ unsigned short f2bf(float f) {
    union { float f; uint32_t u; } v; v.f = f;
    uint32_t u = v.u;
    u += 0x7fffu + ((u >> 16) & 1u);   // RNE
    return (unsigned short)(u >> 16);
}

static __device__ __forceinline__ void gl2lds16(const void* g, void* l) {
    __builtin_amdgcn_global_load_lds(
        (const __attribute__((address_space(1))) uint32_t*)g,
        (__attribute__((address_space(3))) uint32_t*)l, 16, 0, 0);
}

static __device__ __forceinline__ uint2v tr64(unsigned addr) {
    uint2v r;
    asm volatile("ds_read_b64_tr_b16 %0, %1" : "=v"(r) : "v"(addr));
    return r;
}

// ---------------- router part 1: scores = sigmoid(x @ rw^T), fp32 ----------------
__global__ __launch_bounds__(256)
void router_scores_k(const float* __restrict__ x, const float* __restrict__ rw,
                     float* __restrict__ scores, int* __restrict__ counts) {
    if (blockIdx.x == 0 && threadIdx.x < E_NUM) counts[threadIdx.x] = 0;
    int t0 = blockIdx.x * 32;
    __shared__ float xs[32][36];
    __shared__ float wsm[64][36];
    int t = threadIdx.x;
    int tx = t & 15, ty = t >> 4;
    float acc[2][4] = {};
    for (int k0 = 0; k0 < C_DIM; k0 += 32) {
        {
            int r = t >> 3, c = t & 7;
            *(float4*)&xs[r][c * 4] = *(const float4*)(x + (size_t)(t0 + r) * C_DIM + k0 + c * 4);
        }
        #pragma unroll
        for (int i = 0; i < 2; i++) {
            int idx = t + 256 * i;
            int r = idx >> 3, c = idx & 7;
            *(float4*)&wsm[r][c * 4] = *(const float4*)(rw + (size_t)r * C_DIM + k0 + c * 4);
        }
        __syncthreads();
        #pragma unroll
        for (int kk = 0; kk < 32; kk += 4) {
            float4 a0 = *(const float4*)&xs[ty * 2 + 0][kk];
            float4 a1 = *(const float4*)&xs[ty * 2 + 1][kk];
            #pragma unroll
            for (int j = 0; j < 4; j++) {
                float4 b = *(const float4*)&wsm[tx * 4 + j][kk];
                acc[0][j] += a0.x * b.x + a0.y * b.y + a0.z * b.z + a0.w * b.w;
                acc[1][j] += a1.x * b.x + a1.y * b.y + a1.z * b.z + a1.w * b.w;
            }
        }
        __syncthreads();
    }
    #pragma unroll
    for (int i = 0; i < 2; i++)
        #pragma unroll
        for (int j = 0; j < 4; j++)
            scores[(size_t)(t0 + ty * 2 + i) * E_NUM + tx * 4 + j] =
                1.f / (1.f + __expf(-acc[i][j]));
}

// ---------------- router part 2: wave-parallel grouped top-k ----------------
__global__ __launch_bounds__(256)
void topk_k(const float* __restrict__ scores, const float* __restrict__ ebias,
            int* __restrict__ topk_idx, float* __restrict__ topk_w,
            int* __restrict__ counts) {
    int t = blockIdx.x * 4 + (threadIdx.x >> 6);
    int e = threadIdx.x & 63;
    float sc = scores[(size_t)t * E_NUM + e];
    float sb = sc + ebias[e];
    float m1 = sb, m2 = -1e30f;
    #pragma unroll
    for (int off = 1; off <= 4; off <<= 1) {
        float o1 = __shfl_xor(m1, off);
        float o2 = __shfl_xor(m2, off);
        float hi = fmaxf(m1, o1), lo = fminf(m1, o1);
        m2 = fmaxf(lo, fmaxf(m2, o2));
        m1 = hi;
    }
    float grp = m1 + m2;
    float grpv[8];
    #pragma unroll
    for (int g = 0; g < 8; g++) grpv[g] = __shfl(grp, g * 8);
    unsigned gsel = 0;
    #pragma unroll
    for (int k = 0; k < 4; k++) {
        float best = -1e30f; int bi = 0;
        #pragma unroll
        for (int g = 0; g < 8; g++)
            if (!((gsel >> g) & 1) && grpv[g] > best) { best = grpv[g]; bi = g; }
        gsel |= 1u << bi;
    }
    float val = ((gsel >> (e >> 3)) & 1) ? sb : -1e30f;
    int idx[8]; float sv[8]; float wsum = 0.f;
    #pragma unroll
    for (int k = 0; k < 8; k++) {
        uint32_t u = __float_as_uint(val);
        uint32_t mu = (u & 0x80000000u) ? ~u : (u | 0x80000000u);
        unsigned long long key = ((unsigned long long)mu << 6) | (unsigned long long)(63 - e);
        #pragma unroll
        for (int off = 32; off; off >>= 1) {
            unsigned long long ok = __shfl_xor(key, off);
            if (ok > key) key = ok;
        }
        int win = 63 - (int)(key & 63ull);
        idx[k] = win;
        sv[k] = __shfl(sc, win);
        wsum += sv[k];
        if (e == win) val = -1e30f;
    }
    float inv = 1.f / (wsum + 1e-20f);
    if (e < 8) {
        topk_idx[t * 8 + e] = idx[e];
        topk_w[t * 8 + e] = sv[e] * inv;
        atomicAdd(&counts[idx[e]], 1);
    }
}

// exclusive scan over 64 expert counts + m-tile worklist build, one wave
__global__ void scan_k(const int* __restrict__ counts, int* __restrict__ base,
                       int* __restrict__ cursor, int* __restrict__ tile_e,
                       int* __restrict__ tile_m0) {
    int e = threadIdx.x;
    int c = counts[e];
    int s = c;
    #pragma unroll
    for (int off = 1; off < 64; off <<= 1) {
        int o = __shfl_up(s, off);
        if (e >= off) s += o;
    }
    int ex = s - c;
    base[e] = ex;
    cursor[e] = ex;
    int nt = (c + 127) >> 7;
    int ts = nt;
    #pragma unroll
    for (int off = 1; off < 64; off <<= 1) {
        int o = __shfl_up(ts, off);
        if (e >= off) ts += o;
    }
    int tb = ts - nt;
    for (int i = 0; i < nt; i++) { tile_e[tb + i] = e; tile_m0[tb + i] = i * 128; }
    int total = __shfl(ts, 63);
    for (int j = total + e; j < T_TILES; j += 64) tile_e[j] = -1;
}

__global__ void scatter_k(const int* __restrict__ topk_idx, const float* __restrict__ topk_w,
                          int* __restrict__ cursor, int* __restrict__ row_token,
                          float* __restrict__ row_wgt, int* __restrict__ pos_of) {
    int i = blockIdx.x * blockDim.x + threadIdx.x;
    int e = topk_idx[i];
    int pos = atomicAdd(&cursor[e], 1);
    row_token[pos] = i >> 3;
    row_wgt[pos] = topk_w[i];
    pos_of[i] = pos;
}

// ---------------- combine: out[t] += sum_k O[pos_of[t*8+k]] (weights pre-applied) ---
__global__ __launch_bounds__(256)
void combine_k(const float* __restrict__ O, const int* __restrict__ pos_of,
               float* __restrict__ out) {
    int t = blockIdx.x;
    int c = threadIdx.x;
    float4 s = ((const float4*)(out + (size_t)t * C_DIM))[c];
    int p[8];
    #pragma unroll
    for (int k = 0; k < 8; k++) p[k] = pos_of[t * 8 + k];
    #pragma unroll
    for (int k = 0; k < 8; k++) {
        float4 v = ((const float4*)(O + (size_t)p[k] * C_DIM))[c];
        s.x += v.x; s.y += v.y; s.z += v.z; s.w += v.w;
    }
    ((float4*)(out + (size_t)t * C_DIM))[c] = s;
}

// ---------------- prepass: fp32 -> bf16 elementwise (layout-preserving) ----------
__global__ void cvt_bf16_k(const float* __restrict__ in, unsigned short* __restrict__ out, int n8) {
    int i = blockIdx.x * blockDim.x + threadIdx.x;
    if (i >= n8) return;
    float4 v0 = ((const float4*)in)[2 * i];
    float4 v1 = ((const float4*)in)[2 * i + 1];
    unsigned short t[8] = { f2bf(v0.x), f2bf(v0.y), f2bf(v0.z), f2bf(v0.w),
                            f2bf(v1.x), f2bf(v1.y), f2bf(v1.z), f2bf(v1.w) };
    ((uint4*)out)[i] = *(uint4*)t;
}

// ---------------- GEMM: C[M,N] = A[M,K](bf16 [M][K]) @ B(bf16 [K][N]), fp32 acc ----
// A: [128][32] linear LDS via gl2lds (unchanged from R12). B: gl2lds from
// [K][N] bf16 with per-lane swizzled global source -> subtiled LDS
// [kc][nc][4][16]; fragments via 2x ds_read_b64_tr_b16 (R11-proven addressing).
// 3-slot ring, 2-deep prefetch, counted vmcnt(4) + raw barriers (R12 schedule).
// EPI: 0 = SwiGLU(acc1)*acc2 -> bf16; 1 = f32 store; 2 = f32 scaled store
template<bool FUSED, bool GATHER, bool WL, int EPI>
__global__ __launch_bounds__(256, 3)
void gemm2_k(const short* __restrict__ A, const short* __restrict__ B1b,
             const short* __restrict__ B2b, void* __restrict__ Cout,
             int M, int N, int K,
             const int* __restrict__ counts, const int* __restrict__ base,
             const int* __restrict__ row_token, const float* __restrict__ row_wgt,
             const int* __restrict__ tile_e, const int* __restrict__ tile_m0) {
    constexpr int BN = FUSED ? 64 : 128;
    constexpr int NJ = FUSED ? 2 : 4;
    constexpr int NC = BN / 16;            // n-chunks per k-chunk row
    constexpr int BS = BN * 32;            // B LDS shorts per slot (per matrix)

    int e = 0, m0, Mrows, rowbase = 0;
    if (WL) {
        e = tile_e[blockIdx.y];
        if (e < 0) return;
        m0 = tile_m0[blockIdx.y];
        Mrows = counts[e];
        rowbase = base[e];
    } else {
        m0 = blockIdx.y * 128;
        Mrows = M;
    }
    int n0 = blockIdx.x * BN;
    const short* B1 = B1b + (WL ? (size_t)e * N * K : 0);
    const short* B2 = FUSED ? (B2b + (WL ? (size_t)e * N * K : 0)) : nullptr;

    __shared__ short As[3 * 4096];                       // 3 x 128x32
    __shared__ short Bs1[FUSED ? 3 * 2048 : 3 * 4096];   // 3 x subtiled 32xBN
    __shared__ short Bs2[FUSED ? 3 * 2048 : 16];

    int tid = threadIdx.x;
    int lane = tid & 63, w = tid >> 6;
    int wr = w >> 1, wc = w & 1;
    int quad = lane >> 4, l16 = lane & 15;
    int sr = lane >> 2, sc = lane & 3;

    // A staging pointers (unchanged)
    const short* aptr[2];
    #pragma unroll
    for (int i = 0; i < 2; i++) {
        int row = w * 32 + i * 16 + sr;
        int mrow = m0 + row;
        int cl = mrow < Mrows ? mrow : (Mrows - 1);
        size_t arow;
        if (GATHER)  arow = (size_t)row_token[rowbase + cl];
        else if (WL) arow = (size_t)(rowbase + cl);
        else         arow = (size_t)mrow;
        aptr[i] = A + arow * K + sc * 8;
    }

    // B staging pointers: per-lane source so linear lane*16B LDS writes land
    // subtiled. Lane L of wave w carries row kc*4+r, cols nc*16+c..c+7.
    const short* b1ptr[2];
    const short* b2ptr;
    {
        int L = lane;
        int r = (L & 7) >> 1, c = (L & 1) * 8;
        if constexpr (FUSED) {
            int kc = w * 2 + (L >> 5);
            int nc = (L >> 3) & 3;
            b1ptr[0] = B1 + (size_t)(kc * 4 + r) * N + n0 + nc * 16 + c;
            b2ptr    = B2 + (size_t)(kc * 4 + r) * N + n0 + nc * 16 + c;
        } else {
            int nc = L >> 3;
            #pragma unroll
            for (int i = 0; i < 2; i++) {
                int kc = w * 2 + i;
                b1ptr[i] = B1 + (size_t)(kc * 4 + r) * N + n0 + nc * 16 + c;
            }
            b2ptr = nullptr;
        }
    }

    f32x4 acc1[4][NJ] = {};
    f32x4 acc2[FUSED ? 4 : 1][NJ] = {};

    const int nk = K >> 5;
    auto stage = [&](int slot) {
        #pragma unroll
        for (int i = 0; i < 2; i++) {
            gl2lds16(aptr[i], &As[slot * 4096 + (w * 32 + i * 16) * 32]);
            aptr[i] += 32;
        }
        if constexpr (FUSED) {
            gl2lds16(b1ptr[0], &Bs1[slot * 2048 + w * 512]); b1ptr[0] += 32 * N;
            gl2lds16(b2ptr,    &Bs2[slot * 2048 + w * 512]); b2ptr += 32 * N;
        } else {
            #pragma unroll
            for (int i = 0; i < 2; i++) {
                gl2lds16(b1ptr[i], &Bs1[slot * 4096 + (w * 2 + i) * 512]);
                b1ptr[i] += 32 * N;
            }
        }
    };
    stage(0);
    if (nk > 1) stage(1);

    // tr-read lane base (R11-proven): lane addr = subtile base + l16*8 bytes;
    // group (quad) subtile = kc 2*quad; hi read at +NC*128 bytes (kc+1).
    unsigned trb1 = (unsigned)(size_t)&Bs1[0] + (unsigned)(quad * 2 * NC * 128 + l16 * 8);
    unsigned trb2 = FUSED ? ((unsigned)(size_t)&Bs2[0] + (unsigned)(quad * 2 * NC * 128 + l16 * 8)) : 0u;
    auto rdB = [&](unsigned trb, int slot, int nb) -> short8 {
        unsigned a0 = trb + (unsigned)(slot * BS * 2 + nb * 128);
        uint2v lo = tr64(a0);
        uint2v hi = tr64(a0 + NC * 128);
        union { uint32_t u[4]; short8 s; } u;
        u.u[0] = lo[0]; u.u[1] = lo[1]; u.u[2] = hi[0]; u.u[3] = hi[1];
        return u.s;
    };

    int slot = 0, nslot = 2;
    for (int t = 0; t < nk; t++) {
        if (t + 1 < nk) {
            asm volatile("s_waitcnt vmcnt(4)" ::: "memory");
        } else {
            asm volatile("s_waitcnt vmcnt(0)" ::: "memory");
        }
        __builtin_amdgcn_s_barrier();
        __builtin_amdgcn_sched_barrier(0);   // nothing crosses the barrier (rule #18)

        if (t + 2 < nk) stage(nslot);

        short8 a[4], b1[NJ], b2[NJ];
        #pragma unroll
        for (int i = 0; i < 4; i++)
            a[i] = *(const short8*)&As[slot * 4096 + (wr * 64 + i * 16 + l16) * 32 + quad * 8];
        #pragma unroll
        for (int j = 0; j < NJ; j++) {
            int nb = wc * (BN / 32) + j;
            b1[j] = rdB(trb1, slot, nb);
            if constexpr (FUSED) b2[j] = rdB(trb2, slot, nb);
        }
        asm volatile("s_waitcnt lgkmcnt(0)" ::: "memory");
        __builtin_amdgcn_sched_barrier(0);   // rule #18: fence asm ds reads vs MFMA
        #pragma unroll
        for (int i = 0; i < 4; i++)
            #pragma unroll
            for (int j = 0; j < NJ; j++) {
                acc1[i][j] = __builtin_amdgcn_mfma_f32_16x16x32_bf16(a[i], b1[j], acc1[i][j], 0, 0, 0);
                if (FUSED)
                    acc2[i][j] = __builtin_amdgcn_mfma_f32_16x16x32_bf16(a[i], b2[j], acc2[i][j], 0, 0, 0);
            }
        slot = (slot == 2) ? 0 : slot + 1;
        nslot = (nslot == 2) ? 0 : nslot + 1;
    }

    constexpr int CB = BN / 2;
    #pragma unroll
    for (int i = 0; i < 4; i++) {
        #pragma unroll
        for (int rr = 0; rr < 4; rr++) {
            int row = m0 + wr * 64 + i * 16 + quad * 4 + rr;
            if (row >= Mrows) continue;
            size_t orow = WL ? (size_t)(rowbase + row) : (size_t)row;
            float scl = 0.f;
            if (EPI == 2) scl = row_wgt[rowbase + row];
            #pragma unroll
            for (int j = 0; j < NJ; j++) {
                int n = n0 + wc * CB + j * 16 + l16;
                float v = acc1[i][j][rr];
                if (EPI == 0) {
                    float u = acc2[i][j][rr];
                    float h = v / (1.f + __expf(-v)) * u;
                    ((unsigned short*)Cout)[orow * N + n] = f2bf(h);
                } else if (EPI == 1) {
                    ((float*)Cout)[orow * N + n] = v;
                } else {
                    ((float*)Cout)[orow * N + n] = v * scl;
                }
            }
        }
    }
}

// ---------------- launch ----------------
extern "C" void kernel_launch(void* const* d_in, const int* in_sizes, int n_in,
                              void* d_out, int out_size, void* d_ws, size_t ws_size,
                              hipStream_t stream) {
    const float* x        = (const float*)d_in[0];
    const float* router_w = (const float*)d_in[1];
    const float* e_bias   = (const float*)d_in[2];
    const float* gate_w   = (const float*)d_in[3];
    const float* up_w     = (const float*)d_in[4];
    const float* down_w   = (const float*)d_in[5];
    const float* sh_gate  = (const float*)d_in[6];
    const float* sh_up    = (const float*)d_in[7];
    const float* sh_down  = (const float*)d_in[8];
    float* out = (float*)d_out;
    char* ws = (char*)d_ws;

    int*   counts    = (int*)(ws);
    int*   base      = (int*)(ws + 256);
    int*   cursor    = (int*)(ws + 512);
    int*   topk_idx  = (int*)(ws + 1024);
    float* topk_w    = (float*)(ws + 1024 + 131072);
    int*   row_token = (int*)(ws + 1024 + 2 * 131072);
    float* row_wgt   = (float*)(ws + 1024 + 3 * 131072);
    float* scoresbuf = (float*)(ws + 1024 + 4 * 131072);           // 1 MB
    int*   pos_of    = (int*)(ws + 1664 * 1024);                   // 128 KB
    int*   tile_e    = (int*)(ws + 1800 * 1024);
    int*   tile_m0   = (int*)(ws + 1808 * 1024);
    const size_t MB = 1u << 20;
    unsigned short* xb        = (unsigned short*)(ws + 2 * MB);    // 8 MB
    unsigned short* Hs        = (unsigned short*)(ws + 10 * MB);   // 16 MB
    unsigned short* Hr        = (unsigned short*)(ws + 26 * MB);   // 32 MB
    unsigned short* sh_gate_b = (unsigned short*)(ws + 58 * MB);   // 4 MB
    unsigned short* sh_up_b   = (unsigned short*)(ws + 62 * MB);   // 4 MB
    unsigned short* sh_down_b = (unsigned short*)(ws + 66 * MB);   // 4 MB
    unsigned short* gate_b    = (unsigned short*)(ws + 70 * MB);   // 64 MB
    unsigned short* up_b      = (unsigned short*)(ws + 134 * MB);  // 64 MB
    unsigned short* down_b    = (unsigned short*)(ws + 198 * MB);  // 64 MB -> 262 MB
    // O overlays gate_b+up_b (dead after routed fused GEMM): 32768x1024 f32 = 128 MiB
    float* O = (float*)(ws + 70 * MB);

    // ---- routing ----
    router_scores_k<<<S_TOK / 32, 256, 0, stream>>>(x, router_w, scoresbuf, counts);
    topk_k<<<S_TOK / 4, 256, 0, stream>>>(scoresbuf, e_bias, topk_idx, topk_w, counts);
    scan_k<<<1, 64, 0, stream>>>(counts, base, cursor, tile_e, tile_m0);
    scatter_k<<<ROWS_TOTAL / 256, 256, 0, stream>>>(topk_idx, topk_w, cursor, row_token, row_wgt, pos_of);

    // ---- prepass: layout-preserving fp32->bf16 converts (NO transpose) ----
    cvt_bf16_k<<<S_TOK * C_DIM / 8 / 256, 256, 0, stream>>>(x, xb, S_TOK * C_DIM / 8);
    const int NW = E_NUM * C_DIM * H_DIM / 8;          // 4,194,304
    cvt_bf16_k<<<NW / 256, 256, 0, stream>>>(gate_w, gate_b, NW);
    cvt_bf16_k<<<NW / 256, 256, 0, stream>>>(up_w,   up_b,   NW);
    cvt_bf16_k<<<NW / 256, 256, 0, stream>>>(down_w, down_b, NW);
    const int NS = C_DIM * HS_DIM / 8;                 // 262,144
    cvt_bf16_k<<<NS / 256, 256, 0, stream>>>(sh_gate, sh_gate_b, NS);
    cvt_bf16_k<<<NS / 256, 256, 0, stream>>>(sh_up,   sh_up_b,   NS);
    cvt_bf16_k<<<NS / 256, 256, 0, stream>>>(sh_down, sh_down_b, NS);

    // ---- shared expert ----
    gemm2_k<true, false, false, 0><<<dim3(HS_DIM / 64, S_TOK / 128, 1), 256, 0, stream>>>(
        (const short*)xb, (const short*)sh_gate_b, (const short*)sh_up_b, Hs,
        S_TOK, HS_DIM, C_DIM, nullptr, nullptr, nullptr, nullptr, nullptr, nullptr);
    gemm2_k<false, false, false, 1><<<dim3(C_DIM / 128, S_TOK / 128, 1), 256, 0, stream>>>(
        (const short*)Hs, (const short*)sh_down_b, nullptr, out,
        S_TOK, C_DIM, HS_DIM, nullptr, nullptr, nullptr, nullptr, nullptr, nullptr);

    // ---- routed experts (worklist-balanced) ----
    gemm2_k<true, true, true, 0><<<dim3(H_DIM / 64, T_TILES, 1), 256, 0, stream>>>(
        (const short*)xb, (const short*)gate_b, (const short*)up_b, Hr,
        0, H_DIM, C_DIM, counts, base, row_token, row_wgt, tile_e, tile_m0);
    gemm2_k<false, false, true, 2><<<dim3(C_DIM / 128, T_TILES, 1), 256, 0, stream>>>(
        (const short*)Hr, (const short*)down_b, nullptr, O,
        0, C_DIM, H_DIM, counts, base, row_token, row_wgt, tile_e, tile_m0);

    // ---- combine routed into out (out already holds shared-expert result) ----
    combine_k<<<S_TOK, 256, 0, stream>>>(O, pos_of, out);
}

// Round 12
// 916.970 us; speedup vs baseline: 1.0373x; 1.0289x over previous
//
#include <hip/hip_runtime.h>
#include <hip/hip_bf16.h>
#include <stdint.h>

// MoE FFN: sigmoid router (group-limited greedy top-8 of 64), SwiGLU experts
// (1024->512->1024) + shared expert (1024->2048->1024). All inputs fp32.
// R15: DISPATCH CONSOLIDATION 15 -> 8. ~350-400us of runtime has never been
// visible in top-5 across 12 rounds; candidates are block-wave tail
// quantization (shared fused: 1024 blocks on 768-concurrent = 1.33->2 waves)
// and per-launch gaps. Now: ONE cvt_all_k (x + 6 weights), ONE fused_all_k
// (routed 2560 blocks + shared 1024 blocks, single 1D grid, runtime
// N/gather), ONE down_all_k (routed K=512 EPI2 + shared K=2048 EPI1).
// Tails merge; every big dispatch lands in top-5 next round.
// GEMM inner loop = R14 (tr-read B, pre-swizzled gl2lds, vmcnt(4) ring).

#define S_TOK 4096
#define C_DIM 1024
#define E_NUM 64
#define H_DIM 512
#define HS_DIM 2048
#define ROWS_TOTAL (S_TOK * 8)
#define T_TILES 320
#define NB_ROUTED_F (T_TILES * 8)     // 2560 fused routed blocks
#define NB_SHARED_F (32 * 32)         // 1024 fused shared blocks (m 32 x n 32)
#define NB_ROUTED_D (T_TILES * 8)     // 2560 down routed blocks
#define NB_SHARED_D (32 * 8)          // 256 down shared blocks

typedef __attribute__((ext_vector_type(8))) short short8;
typedef __attribute__((ext_vector_type(4))) float f32x4;
typedef __attribute__((ext_vector_type(2))) unsigned int uint2v;

static __device__ __forceinline__ unsigned short f2bf(float f) {
    union { float f; uint32_t u; } v; v.f = f;
    uint32_t u = v.u;
    u += 0x7fffu + ((u >> 16) & 1u);   // RNE
    return (unsigned short)(u >> 16);
}

static __device__ __forceinline__ void gl2lds16(const void* g, void* l) {
    __builtin_amdgcn_global_load_lds(
        (const __attribute__((address_space(1))) uint32_t*)g,
        (__attribute__((address_space(3))) uint32_t*)l, 16, 0, 0);
}

static __device__ __forceinline__ uint2v tr64(unsigned addr) {
    uint2v r;
    asm volatile("ds_read_b64_tr_b16 %0, %1" : "=v"(r) : "v"(addr));
    return r;
}

// ---------------- router part 1: scores = sigmoid(x @ rw^T), fp32 ----------------
__global__ __launch_bounds__(256)
void router_scores_k(const float* __restrict__ x, const float* __restrict__ rw,
                     float* __restrict__ scores, int* __restrict__ counts) {
    if (blockIdx.x == 0 && threadIdx.x < E_NUM) counts[threadIdx.x] = 0;
    int t0 = blockIdx.x * 32;
    __shared__ float xs[32][36];
    __shared__ float wsm[64][36];
    int t = threadIdx.x;
    int tx = t & 15, ty = t >> 4;
    float acc[2][4] = {};
    for (int k0 = 0; k0 < C_DIM; k0 += 32) {
        {
            int r = t >> 3, c = t & 7;
            *(float4*)&xs[r][c * 4] = *(const float4*)(x + (size_t)(t0 + r) * C_DIM + k0 + c * 4);
        }
        #pragma unroll
        for (int i = 0; i < 2; i++) {
            int idx = t + 256 * i;
            int r = idx >> 3, c = idx & 7;
            *(float4*)&wsm[r][c * 4] = *(const float4*)(rw + (size_t)r * C_DIM + k0 + c * 4);
        }
        __syncthreads();
        #pragma unroll
        for (int kk = 0; kk < 32; kk += 4) {
            float4 a0 = *(const float4*)&xs[ty * 2 + 0][kk];
            float4 a1 = *(const float4*)&xs[ty * 2 + 1][kk];
            #pragma unroll
            for (int j = 0; j < 4; j++) {
                float4 b = *(const float4*)&wsm[tx * 4 + j][kk];
                acc[0][j] += a0.x * b.x + a0.y * b.y + a0.z * b.z + a0.w * b.w;
                acc[1][j] += a1.x * b.x + a1.y * b.y + a1.z * b.z + a1.w * b.w;
            }
        }
        __syncthreads();
    }
    #pragma unroll
    for (int i = 0; i < 2; i++)
        #pragma unroll
        for (int j = 0; j < 4; j++)
            scores[(size_t)(t0 + ty * 2 + i) * E_NUM + tx * 4 + j] =
                1.f / (1.f + __expf(-acc[i][j]));
}

// ---------------- router part 2: wave-parallel grouped top-k ----------------
__global__ __launch_bounds__(256)
void topk_k(const float* __restrict__ scores, const float* __restrict__ ebias,
            int* __restrict__ topk_idx, float* __restrict__ topk_w,
            int* __restrict__ counts) {
    int t = blockIdx.x * 4 + (threadIdx.x >> 6);
    int e = threadIdx.x & 63;
    float sc = scores[(size_t)t * E_NUM + e];
    float sb = sc + ebias[e];
    float m1 = sb, m2 = -1e30f;
    #pragma unroll
    for (int off = 1; off <= 4; off <<= 1) {
        float o1 = __shfl_xor(m1, off);
        float o2 = __shfl_xor(m2, off);
        float hi = fmaxf(m1, o1), lo = fminf(m1, o1);
        m2 = fmaxf(lo, fmaxf(m2, o2));
        m1 = hi;
    }
    float grp = m1 + m2;
    float grpv[8];
    #pragma unroll
    for (int g = 0; g < 8; g++) grpv[g] = __shfl(grp, g * 8);
    unsigned gsel = 0;
    #pragma unroll
    for (int k = 0; k < 4; k++) {
        float best = -1e30f; int bi = 0;
        #pragma unroll
        for (int g = 0; g < 8; g++)
            if (!((gsel >> g) & 1) && grpv[g] > best) { best = grpv[g]; bi = g; }
        gsel |= 1u << bi;
    }
    float val = ((gsel >> (e >> 3)) & 1) ? sb : -1e30f;
    int idx[8]; float sv[8]; float wsum = 0.f;
    #pragma unroll
    for (int k = 0; k < 8; k++) {
        uint32_t u = __float_as_uint(val);
        uint32_t mu = (u & 0x80000000u) ? ~u : (u | 0x80000000u);
        unsigned long long key = ((unsigned long long)mu << 6) | (unsigned long long)(63 - e);
        #pragma unroll
        for (int off = 32; off; off >>= 1) {
            unsigned long long ok = __shfl_xor(key, off);
            if (ok > key) key = ok;
        }
        int win = 63 - (int)(key & 63ull);
        idx[k] = win;
        sv[k] = __shfl(sc, win);
        wsum += sv[k];
        if (e == win) val = -1e30f;
    }
    float inv = 1.f / (wsum + 1e-20f);
    if (e < 8) {
        topk_idx[t * 8 + e] = idx[e];
        topk_w[t * 8 + e] = sv[e] * inv;
        atomicAdd(&counts[idx[e]], 1);
    }
}

// exclusive scan over 64 expert counts + m-tile worklist build, one wave
__global__ void scan_k(const int* __restrict__ counts, int* __restrict__ base,
                       int* __restrict__ cursor, int* __restrict__ tile_e,
                       int* __restrict__ tile_m0) {
    int e = threadIdx.x;
    int c = counts[e];
    int s = c;
    #pragma unroll
    for (int off = 1; off < 64; off <<= 1) {
        int o = __shfl_up(s, off);
        if (e >= off) s += o;
    }
    int ex = s - c;
    base[e] = ex;
    cursor[e] = ex;
    int nt = (c + 127) >> 7;
    int ts = nt;
    #pragma unroll
    for (int off = 1; off < 64; off <<= 1) {
        int o = __shfl_up(ts, off);
        if (e >= off) ts += o;
    }
    int tb = ts - nt;
    for (int i = 0; i < nt; i++) { tile_e[tb + i] = e; tile_m0[tb + i] = i * 128; }
    int total = __shfl(ts, 63);
    for (int j = total + e; j < T_TILES; j += 64) tile_e[j] = -1;
}

__global__ void scatter_k(const int* __restrict__ topk_idx, const float* __restrict__ topk_w,
                          int* __restrict__ cursor, int* __restrict__ row_token,
                          float* __restrict__ row_wgt, int* __restrict__ pos_of) {
    int i = blockIdx.x * blockDim.x + threadIdx.x;
    int e = topk_idx[i];
    int pos = atomicAdd(&cursor[e], 1);
    row_token[pos] = i >> 3;
    row_wgt[pos] = topk_w[i];
    pos_of[i] = pos;
}

// ---------------- combine: out[t] += sum_k O[pos_of[t*8+k]] (weights pre-applied) ---
__global__ __launch_bounds__(256)
void combine_k(const float* __restrict__ O, const int* __restrict__ pos_of,
               float* __restrict__ out) {
    int t = blockIdx.x;
    int c = threadIdx.x;
    float4 s = ((const float4*)(out + (size_t)t * C_DIM))[c];
    int p[8];
    #pragma unroll
    for (int k = 0; k < 8; k++) p[k] = pos_of[t * 8 + k];
    #pragma unroll
    for (int k = 0; k < 8; k++) {
        float4 v = ((const float4*)(O + (size_t)p[k] * C_DIM))[c];
        s.x += v.x; s.y += v.y; s.z += v.z; s.w += v.w;
    }
    ((float4*)(out + (size_t)t * C_DIM))[c] = s;
}

// ---------------- prepass: ONE fp32 -> bf16 cvt over all 7 tensors ----------------
__global__ __launch_bounds__(256)
void cvt_all_k(const float* __restrict__ i0, unsigned short* __restrict__ o0, int n0,
               const float* __restrict__ i1, unsigned short* __restrict__ o1, int n1,
               const float* __restrict__ i2, unsigned short* __restrict__ o2, int n2,
               const float* __restrict__ i3, unsigned short* __restrict__ o3, int n3,
               const float* __restrict__ i4, unsigned short* __restrict__ o4, int n4,
               const float* __restrict__ i5, unsigned short* __restrict__ o5, int n5,
               const float* __restrict__ i6, unsigned short* __restrict__ o6, int n6) {
    int g = blockIdx.x * 256 + threadIdx.x;
    const float* in; unsigned short* out;
    if (g < n0) { in = i0; out = o0; }
    else { g -= n0;
    if (g < n1) { in = i1; out = o1; }
    else { g -= n1;
    if (g < n2) { in = i2; out = o2; }
    else { g -= n2;
    if (g < n3) { in = i3; out = o3; }
    else { g -= n3;
    if (g < n4) { in = i4; out = o4; }
    else { g -= n4;
    if (g < n5) { in = i5; out = o5; }
    else { g -= n5;
    if (g >= n6) return;
    in = i6; out = o6; } } } } } }
    float4 v0 = ((const float4*)in)[2 * g];
    float4 v1 = ((const float4*)in)[2 * g + 1];
    unsigned short t[8] = { f2bf(v0.x), f2bf(v0.y), f2bf(v0.z), f2bf(v0.w),
                            f2bf(v1.x), f2bf(v1.y), f2bf(v1.z), f2bf(v1.w) };
    ((uint4*)out)[g] = *(uint4*)t;
}

// ---------------- unified FUSED gate+up GEMM: routed tiles + shared tiles --------
// bid < NB_ROUTED_F: routed (worklist, gather, N=512); else shared (N=2048).
// Tile 128x64, B via pre-swizzled gl2lds -> subtiled LDS -> ds_read_b64_tr_b16.
__global__ __launch_bounds__(256, 3)
void fused_all_k(const short* __restrict__ xb,
                 const short* __restrict__ gate_b, const short* __restrict__ up_b,
                 const short* __restrict__ shg_b, const short* __restrict__ shu_b,
                 unsigned short* __restrict__ Hr, unsigned short* __restrict__ Hs,
                 const int* __restrict__ counts, const int* __restrict__ base,
                 const int* __restrict__ row_token,
                 const int* __restrict__ tile_e, const int* __restrict__ tile_m0) {
    constexpr int K = C_DIM;
    constexpr int NC = 4;                 // 64/16
    constexpr int BS = 64 * 32;           // B LDS shorts per slot

    int bid = blockIdx.x;
    bool routed = bid < NB_ROUTED_F;
    const short* B1; const short* B2; unsigned short* Cout;
    int m0, n0, Mrows, rowbase, N;
    if (routed) {
        int ti = bid >> 3;
        int e = tile_e[ti];
        if (e < 0) return;
        m0 = tile_m0[ti]; n0 = (bid & 7) * 64;
        Mrows = counts[e]; rowbase = base[e];
        N = H_DIM;
        B1 = gate_b + (size_t)e * H_DIM * K;
        B2 = up_b   + (size_t)e * H_DIM * K;
        Cout = Hr;
    } else {
        int s = bid - NB_ROUTED_F;
        m0 = (s >> 5) * 128; n0 = (s & 31) * 64;
        Mrows = S_TOK; rowbase = 0;
        N = HS_DIM;
        B1 = shg_b; B2 = shu_b;
        Cout = Hs;
    }

    __shared__ short As[3 * 4096];
    __shared__ short Bs1[3 * BS / 2 * 2];   // 3 x 2048
    __shared__ short Bs2[3 * 2048];

    int tid = threadIdx.x;
    int lane = tid & 63, w = tid >> 6;
    int wr = w >> 1, wc = w & 1;
    int quad = lane >> 4, l16 = lane & 15;
    int sr = lane >> 2, sc = lane & 3;

    const short* aptr[2];
    #pragma unroll
    for (int i = 0; i < 2; i++) {
        int row = w * 32 + i * 16 + sr;
        int mrow = m0 + row;
        int cl = mrow < Mrows ? mrow : (Mrows - 1);
        size_t arow = routed ? (size_t)row_token[rowbase + cl] : (size_t)cl;
        aptr[i] = xb + arow * K + sc * 8;
    }

    const short* b1ptr;
    const short* b2ptr;
    {
        int L = lane;
        int r = (L & 7) >> 1, c = (L & 1) * 8;
        int kc = w * 2 + (L >> 5);
        int nc = (L >> 3) & 3;
        b1ptr = B1 + (size_t)(kc * 4 + r) * N + n0 + nc * 16 + c;
        b2ptr = B2 + (size_t)(kc * 4 + r) * N + n0 + nc * 16 + c;
    }
    const size_t bstep = (size_t)32 * N;

    f32x4 acc1[4][2] = {};
    f32x4 acc2[4][2] = {};

    const int nk = K >> 5;
    auto stage = [&](int slot) {
        #pragma unroll
        for (int i = 0; i < 2; i++) {
            gl2lds16(aptr[i], &As[slot * 4096 + (w * 32 + i * 16) * 32]);
            aptr[i] += 32;
        }
        gl2lds16(b1ptr, &Bs1[slot * 2048 + w * 512]); b1ptr += bstep;
        gl2lds16(b2ptr, &Bs2[slot * 2048 + w * 512]); b2ptr += bstep;
    };
    stage(0);
    stage(1);

    unsigned trb1 = (unsigned)(size_t)&Bs1[0] + (unsigned)(quad * 2 * NC * 128 + l16 * 8);
    unsigned trb2 = (unsigned)(size_t)&Bs2[0] + (unsigned)(quad * 2 * NC * 128 + l16 * 8);
    auto rdB = [&](unsigned trb, int slot, int nb) -> short8 {
        unsigned a0 = trb + (unsigned)(slot * 4096 + nb * 128);
        uint2v lo = tr64(a0);
        uint2v hi = tr64(a0 + NC * 128);
        union { uint32_t u[4]; short8 s; } u;
        u.u[0] = lo[0]; u.u[1] = lo[1]; u.u[2] = hi[0]; u.u[3] = hi[1];
        return u.s;
    };

    int slot = 0, nslot = 2;
    for (int t = 0; t < nk; t++) {
        if (t + 1 < nk) {
            asm volatile("s_waitcnt vmcnt(4)" ::: "memory");
        } else {
            asm volatile("s_waitcnt vmcnt(0)" ::: "memory");
        }
        __builtin_amdgcn_s_barrier();
        __builtin_amdgcn_sched_barrier(0);

        if (t + 2 < nk) stage(nslot);

        short8 a[4], b1[2], b2[2];
        #pragma unroll
        for (int i = 0; i < 4; i++)
            a[i] = *(const short8*)&As[slot * 4096 + (wr * 64 + i * 16 + l16) * 32 + quad * 8];
        #pragma unroll
        for (int j = 0; j < 2; j++) {
            int nb = wc * 2 + j;
            b1[j] = rdB(trb1, slot, nb);
            b2[j] = rdB(trb2, slot, nb);
        }
        asm volatile("s_waitcnt lgkmcnt(0)" ::: "memory");
        __builtin_amdgcn_sched_barrier(0);
        #pragma unroll
        for (int i = 0; i < 4; i++)
            #pragma unroll
            for (int j = 0; j < 2; j++) {
                acc1[i][j] = __builtin_amdgcn_mfma_f32_16x16x32_bf16(a[i], b1[j], acc1[i][j], 0, 0, 0);
                acc2[i][j] = __builtin_amdgcn_mfma_f32_16x16x32_bf16(a[i], b2[j], acc2[i][j], 0, 0, 0);
            }
        slot = (slot == 2) ? 0 : slot + 1;
        nslot = (nslot == 2) ? 0 : nslot + 1;
    }

    #pragma unroll
    for (int i = 0; i < 4; i++) {
        #pragma unroll
        for (int rr = 0; rr < 4; rr++) {
            int row = m0 + wr * 64 + i * 16 + quad * 4 + rr;
            if (row >= Mrows) continue;
            size_t orow = (size_t)(rowbase + row);
            #pragma unroll
            for (int j = 0; j < 2; j++) {
                int n = n0 + wc * 32 + j * 16 + l16;
                float v = acc1[i][j][rr];
                float u = acc2[i][j][rr];
                float h = v / (1.f + __expf(-v)) * u;
                Cout[orow * N + n] = f2bf(h);
            }
        }
    }
}

// ---------------- unified DOWN GEMM: routed (K=512, ->O scaled) + shared (K=2048, ->out) --
__global__ __launch_bounds__(256, 3)
void down_all_k(const short* __restrict__ Hr, const short* __restrict__ Hs,
                const short* __restrict__ down_b, const short* __restrict__ shd_b,
                float* __restrict__ O, float* __restrict__ out,
                const int* __restrict__ counts, const int* __restrict__ base,
                const float* __restrict__ row_wgt,
                const int* __restrict__ tile_e, const int* __restrict__ tile_m0) {
    constexpr int N = C_DIM;
    constexpr int NC = 8;                 // 128/16
    constexpr int BS = 128 * 32;          // B LDS shorts per slot

    int bid = blockIdx.x;
    bool routed = bid < NB_ROUTED_D;
    const short* A; const short* B1; float* Cout;
    int m0, n0, Mrows, rowbase, K;
    if (routed) {
        int ti = bid >> 3;
        int e = tile_e[ti];
        if (e < 0) return;
        m0 = tile_m0[ti]; n0 = (bid & 7) * 128;
        Mrows = counts[e]; rowbase = base[e];
        K = H_DIM;
        A = Hr;
        B1 = down_b + (size_t)e * N * H_DIM;
        Cout = O;
    } else {
        int s = bid - NB_ROUTED_D;
        m0 = (s >> 3) * 128; n0 = (s & 7) * 128;
        Mrows = S_TOK; rowbase = 0;
        K = HS_DIM;
        A = Hs;
        B1 = shd_b;
        Cout = out;
    }

    __shared__ short As[3 * 4096];
    __shared__ short Bs1[3 * BS];

    int tid = threadIdx.x;
    int lane = tid & 63, w = tid >> 6;
    int wr = w >> 1, wc = w & 1;
    int quad = lane >> 4, l16 = lane & 15;
    int sr = lane >> 2, sc = lane & 3;

    const short* aptr[2];
    #pragma unroll
    for (int i = 0; i < 2; i++) {
        int row = w * 32 + i * 16 + sr;
        int mrow = m0 + row;
        int cl = mrow < Mrows ? mrow : (Mrows - 1);
        aptr[i] = A + (size_t)(rowbase + cl) * K + sc * 8;
    }

    const short* b1ptr[2];
    {
        int L = lane;
        int r = (L & 7) >> 1, c = (L & 1) * 8;
        int nc = L >> 3;
        #pragma unroll
        for (int i = 0; i < 2; i++) {
            int kc = w * 2 + i;
            b1ptr[i] = B1 + (size_t)(kc * 4 + r) * N + n0 + nc * 16 + c;
        }
    }
    const size_t bstep = (size_t)32 * N;

    f32x4 acc1[4][4] = {};

    const int nk = K >> 5;
    auto stage = [&](int slot) {
        #pragma unroll
        for (int i = 0; i < 2; i++) {
            gl2lds16(aptr[i], &As[slot * 4096 + (w * 32 + i * 16) * 32]);
            aptr[i] += 32;
        }
        #pragma unroll
        for (int i = 0; i < 2; i++) {
            gl2lds16(b1ptr[i], &Bs1[slot * BS + (w * 2 + i) * 512]);
            b1ptr[i] += bstep;
        }
    };
    stage(0);
    stage(1);

    unsigned trb1 = (unsigned)(size_t)&Bs1[0] + (unsigned)(quad * 2 * NC * 128 + l16 * 8);
    auto rdB = [&](int slot, int nb) -> short8 {
        unsigned a0 = trb1 + (unsigned)(slot * BS * 2 + nb * 128);
        uint2v lo = tr64(a0);
        uint2v hi = tr64(a0 + NC * 128);
        union { uint32_t u[4]; short8 s; } u;
        u.u[0] = lo[0]; u.u[1] = lo[1]; u.u[2] = hi[0]; u.u[3] = hi[1];
        return u.s;
    };

    int slot = 0, nslot = 2;
    for (int t = 0; t < nk; t++) {
        if (t + 1 < nk) {
            asm volatile("s_waitcnt vmcnt(4)" ::: "memory");
        } else {
            asm volatile("s_waitcnt vmcnt(0)" ::: "memory");
        }
        __builtin_amdgcn_s_barrier();
        __builtin_amdgcn_sched_barrier(0);

        if (t + 2 < nk) stage(nslot);

        short8 a[4], b1[4];
        #pragma unroll
        for (int i = 0; i < 4; i++)
            a[i] = *(const short8*)&As[slot * 4096 + (wr * 64 + i * 16 + l16) * 32 + quad * 8];
        #pragma unroll
        for (int j = 0; j < 4; j++)
            b1[j] = rdB(slot, wc * 4 + j);
        asm volatile("s_waitcnt lgkmcnt(0)" ::: "memory");
        __builtin_amdgcn_sched_barrier(0);
        #pragma unroll
        for (int i = 0; i < 4; i++)
            #pragma unroll
            for (int j = 0; j < 4; j++)
                acc1[i][j] = __builtin_amdgcn_mfma_f32_16x16x32_bf16(a[i], b1[j], acc1[i][j], 0, 0, 0);
        slot = (slot == 2) ? 0 : slot + 1;
        nslot = (nslot == 2) ? 0 : nslot + 1;
    }

    #pragma unroll
    for (int i = 0; i < 4; i++) {
        #pragma unroll
        for (int rr = 0; rr < 4; rr++) {
            int row = m0 + wr * 64 + i * 16 + quad * 4 + rr;
            if (row >= Mrows) continue;
            size_t orow = (size_t)(rowbase + row);
            float scl = routed ? row_wgt[rowbase + row] : 1.f;
            #pragma unroll
            for (int j = 0; j < 4; j++) {
                int n = n0 + wc * 64 + j * 16 + l16;
                Cout[orow * N + n] = acc1[i][j][rr] * scl;
            }
        }
    }
}

// ---------------- launch ----------------
extern "C" void kernel_launch(void* const* d_in, const int* in_sizes, int n_in,
                              void* d_out, int out_size, void* d_ws, size_t ws_size,
                              hipStream_t stream) {
    const float* x        = (const float*)d_in[0];
    const float* router_w = (const float*)d_in[1];
    const float* e_bias   = (const float*)d_in[2];
    const float* gate_w   = (const float*)d_in[3];
    const float* up_w     = (const float*)d_in[4];
    const float* down_w   = (const float*)d_in[5];
    const float* sh_gate  = (const float*)d_in[6];
    const float* sh_up    = (const float*)d_in[7];
    const float* sh_down  = (const float*)d_in[8];
    float* out = (float*)d_out;
    char* ws = (char*)d_ws;

    int*   counts    = (int*)(ws);
    int*   base      = (int*)(ws + 256);
    int*   cursor    = (int*)(ws + 512);
    int*   topk_idx  = (int*)(ws + 1024);
    float* topk_w    = (float*)(ws + 1024 + 131072);
    int*   row_token = (int*)(ws + 1024 + 2 * 131072);
    float* row_wgt   = (float*)(ws + 1024 + 3 * 131072);
    float* scoresbuf = (float*)(ws + 1024 + 4 * 131072);           // 1 MB
    int*   pos_of    = (int*)(ws + 1664 * 1024);                   // 128 KB
    int*   tile_e    = (int*)(ws + 1800 * 1024);
    int*   tile_m0   = (int*)(ws + 1808 * 1024);
    const size_t MB = 1u << 20;
    unsigned short* xb        = (unsigned short*)(ws + 2 * MB);    // 8 MB
    unsigned short* Hs        = (unsigned short*)(ws + 10 * MB);   // 16 MB
    unsigned short* Hr        = (unsigned short*)(ws + 26 * MB);   // 32 MB
    unsigned short* sh_gate_b = (unsigned short*)(ws + 58 * MB);   // 4 MB
    unsigned short* sh_up_b   = (unsigned short*)(ws + 62 * MB);   // 4 MB
    unsigned short* sh_down_b = (unsigned short*)(ws + 66 * MB);   // 4 MB
    unsigned short* gate_b    = (unsigned short*)(ws + 70 * MB);   // 64 MB
    unsigned short* up_b      = (unsigned short*)(ws + 134 * MB);  // 64 MB
    unsigned short* down_b    = (unsigned short*)(ws + 198 * MB);  // 64 MB -> 262 MB
    // O overlays gate_b+up_b (dead after fused_all): 32768x1024 f32 = 128 MiB
    float* O = (float*)(ws + 70 * MB);

    // ---- routing ----
    router_scores_k<<<S_TOK / 32, 256, 0, stream>>>(x, router_w, scoresbuf, counts);
    topk_k<<<S_TOK / 4, 256, 0, stream>>>(scoresbuf, e_bias, topk_idx, topk_w, counts);
    scan_k<<<1, 64, 0, stream>>>(counts, base, cursor, tile_e, tile_m0);
    scatter_k<<<ROWS_TOTAL / 256, 256, 0, stream>>>(topk_idx, topk_w, cursor, row_token, row_wgt, pos_of);

    // ---- prepass: single fp32->bf16 cvt over all 7 tensors ----
    const int NX = S_TOK * C_DIM / 8;                  // 524288
    const int NW = E_NUM * C_DIM * H_DIM / 8;          // 4194304
    const int NS = C_DIM * HS_DIM / 8;                 // 262144
    const int NTOT = NX + 3 * NW + 3 * NS;
    cvt_all_k<<<(NTOT + 255) / 256, 256, 0, stream>>>(
        x, xb, NX, gate_w, gate_b, NW, up_w, up_b, NW, down_w, down_b, NW,
        sh_gate, sh_gate_b, NS, sh_up, sh_up_b, NS, sh_down, sh_down_b, NS);

    // ---- unified fused gate+up (routed + shared) ----
    fused_all_k<<<NB_ROUTED_F + NB_SHARED_F, 256, 0, stream>>>(
        (const short*)xb, (const short*)gate_b, (const short*)up_b,
        (const short*)sh_gate_b, (const short*)sh_up_b, Hr, Hs,
        counts, base, row_token, tile_e, tile_m0);

    // ---- unified down (routed -> O scaled, shared -> out) ----
    down_all_k<<<NB_ROUTED_D + NB_SHARED_D, 256, 0, stream>>>(
        (const short*)Hr, (const short*)Hs, (const short*)down_b, (const short*)sh_down_b,
        O, out, counts, base, row_wgt, tile_e, tile_m0);

    // ---- combine routed into out (out already holds shared-expert result) ----
    combine_k<<<S_TOK, 256, 0, stream>>>(O, pos_of, out);
}